// Round 12
// baseline (363.494 us; speedup 1.0000x reference)
//
#include <hip/hip_runtime.h>
#include <hip/hip_bf16.h>
#include <math.h>

#define BB 4
#define TT 2048
#define DD 1024
#define DLb 128
#define EE 8
#define HH 4
#define KK 3
#define HDh 32
#define NN (BB*TT)
#define NPOS 9
#define NCH 16
#define CHL (TT/NCH)
#define SEQSTR (NPOS*DLb)   // 1152

typedef __attribute__((ext_vector_type(8))) short short8;
typedef __attribute__((ext_vector_type(4))) float f32x4;
typedef __attribute__((ext_vector_type(8))) unsigned short ushort8;
typedef __attribute__((ext_vector_type(4))) unsigned short ushort4v;

// async global->LDS DMA, 16B per lane; LDS dest = wave-uniform base + lane*16
#define GLL(gptr, lptr) \
    __builtin_amdgcn_global_load_lds((const __attribute__((address_space(1))) unsigned int*)(gptr), \
                                     (__attribute__((address_space(3))) unsigned int*)(lptr), 16, 0, 0)

__device__ __forceinline__ float gelu_exact(float v) {
    return 0.5f * v * (1.0f + erff(v * 0.70710678118654752440f));
}

__device__ __forceinline__ unsigned short f2bf(float x) {
    __hip_bfloat16 h = __float2bfloat16(x);
    return *reinterpret_cast<unsigned short*>(&h);
}

__device__ __forceinline__ float bf2f(unsigned short u) {
    return __uint_as_float(((unsigned int)u) << 16);
}

__device__ __forceinline__ float4 rec4(const unsigned short* h, const unsigned short* l) {
    ushort4v hv = *(const ushort4v*)h;
    ushort4v lv = *(const ushort4v*)l;
    float4 r;
    r.x = bf2f(hv[0]) + bf2f(lv[0]);
    r.y = bf2f(hv[1]) + bf2f(lv[1]);
    r.z = bf2f(hv[2]) + bf2f(lv[2]);
    r.w = bf2f(hv[3]) + bf2f(lv[3]);
    return r;
}

// --- swizzled staging: 512-thread variant. Panel = 128 rows x 32 cols bf16 (8KB).
// LDS stays linear (GLL requirement); the 16B-chunk permutation is applied on the
// GLOBAL source address (chunk slot s of row r holds global chunk s ^ ((r>>1)&3)).
// Readers apply the same XOR (involution) -> bank-conflict-free fragment reads.
__device__ __forceinline__ void stage512(const unsigned short* __restrict__ G,
                                         size_t rowBase, int L, int k0,
                                         unsigned short* lds, int tid)
{
    int r = tid >> 2;                       // 0..127
    int sl = tid & 3;                       // chunk slot in LDS
    int src = sl ^ ((r >> 1) & 3);          // which global chunk lands here
    GLL(&G[(rowBase + r) * (size_t)L + k0 + src * 8], lds + (tid >> 6) * 512);
}

// fragment-read LDS offset (shorts) for row, chunk fq under the stage512 swizzle
__device__ __forceinline__ int fragoff(int row, int fq) {
    return row * 32 + ((fq ^ ((row >> 1) & 3)) << 3);
}

// ---------------- K0: fused fp32 -> (hi,lo) bf16 split for two tensors ----------------
__global__ __launch_bounds__(256) void ksplit2(const float* __restrict__ s1,
                                               unsigned short* __restrict__ h1,
                                               unsigned short* __restrict__ l1, int n8_1,
                                               const float* __restrict__ s2,
                                               unsigned short* __restrict__ h2,
                                               unsigned short* __restrict__ l2, int n8_2)
{
    int i = blockIdx.x * 256 + threadIdx.x;
    const float* src;
    unsigned short* h;
    unsigned short* l;
    int idx;
    if (i < n8_1) { src = s1; h = h1; l = l1; idx = i; }
    else {
        idx = i - n8_1;
        if (idx >= n8_2) return;
        src = s2; h = h2; l = l2;
    }
    size_t g = (size_t)idx * 8;
    float4 a = *(const float4*)&src[g];
    float4 b = *(const float4*)&src[g + 4];
    float vv[8] = {a.x, a.y, a.z, a.w, b.x, b.y, b.z, b.w};
    ushort8 ho, lo;
    #pragma unroll
    for (int j = 0; j < 8; j++) {
        unsigned short hh = f2bf(vv[j]);
        float hf = bf2f(hh);
        ho[j] = hh;
        lo[j] = f2bf(vv[j] - hf);
    }
    *(ushort8*)&h[g] = ho;
    *(ushort8*)&l[g] = lo;
}

// ---------------- K1: per-batch column mean of x + fused hi/lo split ----------------
__global__ __launch_bounds__(256) void k1a(const float* __restrict__ x, float* __restrict__ partial,
                                           unsigned short* __restrict__ xh,
                                           unsigned short* __restrict__ xl) {
    int d = blockIdx.x * 256 + threadIdx.x;
    int b = blockIdx.y, c = blockIdx.z;
    size_t base = ((size_t)b * TT + (size_t)c * CHL) * DD + d;
    float s = 0.0f;
    for (int t = 0; t < CHL; t++) {
        size_t idx = base + (size_t)t * DD;
        float v = x[idx];
        s += v;
        unsigned short h = f2bf(v);
        xh[idx] = h;
        xl[idx] = f2bf(v - bf2f(h));
    }
    partial[(b * NCH + c) * DD + d] = s;
}

__global__ __launch_bounds__(256) void k1b(const float* __restrict__ partial, float* __restrict__ mean_x) {
    int d = blockIdx.x * 256 + threadIdx.x;
    int b = blockIdx.y;
    float s = 0.0f;
    for (int c = 0; c < NCH; c++) s += partial[(b * NCH + c) * DD + d];
    mean_x[b * DD + d] = s * (1.0f / TT);
}

// ---------------- K2: per-batch gctx + rq chain + router u-vector ----------------
__global__ __launch_bounds__(128) void k2_batch(
    const float* __restrict__ mean_x,
    const float* __restrict__ gpw, const float* __restrict__ gpb,
    const float* __restrict__ rq1w, const float* __restrict__ rq1b,
    const float* __restrict__ lnw, const float* __restrict__ lnb,
    const float* __restrict__ rq2w, const float* __restrict__ rq2b,
    const float* __restrict__ rkw, const float* __restrict__ rkb,
    float* __restrict__ gctx, float* __restrict__ uv, float* __restrict__ c0v)
{
    int b = blockIdx.x, d = threadIdx.x;
    __shared__ __attribute__((aligned(16))) float g[DLb];
    __shared__ __attribute__((aligned(16))) float t1[DLb];
    __shared__ __attribute__((aligned(16))) float act[DLb];
    __shared__ __attribute__((aligned(16))) float rqs[DLb];
    __shared__ float red[2];
    {
        const float4* wrow = (const float4*)(gpw + (size_t)d * DD);
        const float4* mx4  = (const float4*)(mean_x + (size_t)b * DD);
        float s = gpb[d];
        for (int k = 0; k < DD / 4; k++) {
            float4 w = wrow[k], m = mx4[k];
            s += w.x * m.x + w.y * m.y + w.z * m.z + w.w * m.w;
        }
        g[d] = s;
        gctx[b * DLb + d] = s;
    }
    __syncthreads();
    {
        float s = rq1b[d];
        for (int k = 0; k < DLb; k++) s += g[k] * rq1w[d * DLb + k];
        t1[d] = s;
    }
    __syncthreads();
    if (d == 0) {
        float m = 0.0f;
        for (int i = 0; i < DLb; i++) m += t1[i];
        m *= (1.0f / DLb);
        float v = 0.0f;
        for (int i = 0; i < DLb; i++) { float df = t1[i] - m; v += df * df; }
        v *= (1.0f / DLb);
        red[0] = m; red[1] = 1.0f / sqrtf(v + 1e-5f);
    }
    __syncthreads();
    {
        float xn = (t1[d] - red[0]) * red[1] * lnw[d] + lnb[d];
        act[d] = gelu_exact(xn);
    }
    __syncthreads();
    {
        float s = rq2b[d];
        for (int k = 0; k < DLb; k++) s += act[k] * rq2w[d * DLb + k];
        rqs[d] = s;
    }
    __syncthreads();
    // u[d] = sum_k rq[k] * rkw[k][d]  (rkw row-major [k][d] -> rkw[k*DLb + d])
    {
        float u = 0.0f;
        for (int k = 0; k < DLb; k++) u += rqs[k] * rkw[(size_t)k * DLb + d];
        uv[b * DLb + d] = u;
    }
    if (d == 0) {
        float c0 = 0.0f;
        for (int k = 0; k < DLb; k++) c0 += rqs[k] * rkb[k];
        c0v[b] = c0;
    }
}

// ---------------- K3s: seq[:,1:,:] = x @ w_down^T + pe  (+ pos-0 fill from gctx) ----------------
// 8-wave split-bf16 MFMA, BK=64, XCD-chunked block swizzle.
__global__ __launch_bounds__(512, 4) void k3s(const unsigned short* __restrict__ XH,
                                              const unsigned short* __restrict__ XL,
                                              const unsigned short* __restrict__ WH,
                                              const unsigned short* __restrict__ WL,
                                              const float* __restrict__ pe,
                                              const float* __restrict__ gctx,
                                              unsigned short* __restrict__ seqh,
                                              unsigned short* __restrict__ seql)
{
    __shared__ __attribute__((aligned(16))) unsigned short Ah[2][128 * 32];
    __shared__ __attribute__((aligned(16))) unsigned short Al[2][128 * 32];
    __shared__ __attribute__((aligned(16))) unsigned short Bh[2][128 * 32];
    __shared__ __attribute__((aligned(16))) unsigned short Bl[2][128 * 32];
    int tid = threadIdx.x;
    int lane = tid & 63, wave = tid >> 6;     // 8 waves
    int wm = wave & 1, wn = wave >> 1;        // 2 x 4 wave grid -> 64x32 per wave
    // XCD-chunked bijective swizzle: grid (8,64) = 512 blocks, 512%8==0.
    int b = blockIdx.y * 8 + blockIdx.x;
    int nbid = (b & 7) * 64 + (b >> 3);
    int row0 = (nbid >> 3) * 128, col0 = (nbid & 7) * 128;
    int fr = lane & 15, fq = lane >> 4;
    f32x4 acc[4][2];
    #pragma unroll
    for (int i = 0; i < 4; i++)
        #pragma unroll
        for (int j = 0; j < 2; j++) acc[i][j] = (f32x4)0.0f;

    for (int k0 = 0; k0 < DD; k0 += 64) {
        stage512(XH, row0, DD, k0,      Ah[0], tid);
        stage512(XH, row0, DD, k0 + 32, Ah[1], tid);
        stage512(XL, row0, DD, k0,      Al[0], tid);
        stage512(XL, row0, DD, k0 + 32, Al[1], tid);
        stage512(WH, col0, DD, k0,      Bh[0], tid);
        stage512(WH, col0, DD, k0 + 32, Bh[1], tid);
        stage512(WL, col0, DD, k0,      Bl[0], tid);
        stage512(WL, col0, DD, k0 + 32, Bl[1], tid);
        __syncthreads();
        #pragma unroll
        for (int ks = 0; ks < 2; ks++) {
            short8 ah[4], al4[4], bh[2], bl4[2];
            #pragma unroll
            for (int f = 0; f < 4; f++) {
                int ra = fragoff(wm * 64 + f * 16 + fr, fq);
                ah[f]  = *(const short8*)&Ah[ks][ra];
                al4[f] = *(const short8*)&Al[ks][ra];
            }
            #pragma unroll
            for (int g = 0; g < 2; g++) {
                int rb = fragoff(wn * 32 + g * 16 + fr, fq);
                bh[g]  = *(const short8*)&Bh[ks][rb];
                bl4[g] = *(const short8*)&Bl[ks][rb];
            }
            #pragma unroll
            for (int i = 0; i < 4; i++)
                #pragma unroll
                for (int j = 0; j < 2; j++) {
                    acc[i][j] = __builtin_amdgcn_mfma_f32_16x16x32_bf16(ah[i],  bh[j],  acc[i][j], 0, 0, 0);
                    acc[i][j] = __builtin_amdgcn_mfma_f32_16x16x32_bf16(ah[i],  bl4[j], acc[i][j], 0, 0, 0);
                    acc[i][j] = __builtin_amdgcn_mfma_f32_16x16x32_bf16(al4[i], bh[j],  acc[i][j], 0, 0, 0);
                }
        }
        __syncthreads();
    }
    #pragma unroll
    for (int j = 0; j < 2; j++) {
        int gc = col0 + wn * 32 + j * 16 + fr;
        float pv = pe[gc];
        #pragma unroll
        for (int i = 0; i < 4; i++) {
            #pragma unroll
            for (int r = 0; r < 4; r++) {
                int gr = row0 + wm * 64 + i * 16 + fq * 4 + r;
                float v = acc[i][j][r] + pv;
                unsigned short h = f2bf(v);
                size_t idx = (size_t)gr * SEQSTR + DLb + gc;
                seqh[idx] = h;
                seql[idx] = f2bf(v - bf2f(h));
            }
        }
    }
    // pos-0 fill (was k2b): col0==0 blocks write gctx into seq position 0 for
    // their 128 tokens. Disjoint addresses from the epilogue above; same ops.
    if (col0 == 0) {
        #pragma unroll
        for (int it = 0; it < 32; it++) {
            int idx = it * 512 + tid;             // 128 tokens x 128 d
            int n = row0 + (idx >> 7), d = idx & 127;
            float v = gctx[(n >> 11) * DLb + d];
            unsigned short h = f2bf(v);
            seqh[(size_t)n * SEQSTR + d] = h;
            seql[(size_t)n * SEQSTR + d] = f2bf(v - bf2f(h));
        }
    }
}

// ---------------- K4f: fused qkv GEMM + attention (BK=64 GEMM, reuse-mapped PV) ----------------
// Block = 16 tokens = 144 contiguous seq rows. 8 waves, 1x8 layout.
// Round-12: phase 4 remapped to thread=(token, d-quad): each v-row quad is read
// ONCE (9 ds_read_b128/thread, was 72) and reused across the token's 8 output rows
// (s[8] f32x4 accumulators, statically indexed). attnw scalar reads broadcast
// across each (t,h) octet. Per-output j-order and FMA sequence unchanged ->
// o bit-identical to rounds 5/8/11.
__global__ __launch_bounds__(512, 2) void k4f(const unsigned short* __restrict__ SH,
                                              const unsigned short* __restrict__ SL,
                                              const unsigned short* __restrict__ WHp,
                                              const unsigned short* __restrict__ WLp,
                                              const float* __restrict__ bias,
                                              float* __restrict__ og)
{
    // LDS: 40512 floats = 162,048 B (<= 163,840)
    //  [0, 16896)        qbuf [128][132]   (alias: Ah/Al BK=64 staging; vbuf phase>=3)
    //  [16896, 35904)    kbuf [144][132]
    //  [35904, 40512)    attnw [16][4][8][9]
    __shared__ __attribute__((aligned(16))) float smemf[40512];
    float* qbuf  = smemf;
    float* kbuf  = smemf + 128 * 132;
    float* attnw = smemf + 128 * 132 + 144 * 132;
    float* vbuf  = smemf;                                   // alias (phase >= 3), [144][132]
    unsigned short* Ah = (unsigned short*)smemf;            // [144*64] shorts (4608 floats)
    unsigned short* Al = (unsigned short*)(smemf + 4608);   // [144*64] shorts

    int tid = threadIdx.x;
    int lane = tid & 63, w = tid >> 6;
    int fr = lane & 15, fq = lane >> 4;
    int colBase = w * 48;
    size_t rowBase = (size_t)blockIdx.x * 144;

    f32x4 acc[9][3];
    #pragma unroll
    for (int i = 0; i < 9; i++)
        #pragma unroll
        for (int g = 0; g < 3; g++) acc[i][g] = (f32x4)0.0f;

    for (int k0 = 0; k0 < DLb; k0 += 64) {
        // stage A: 144 rows x 64 cols (hi/lo) = 1152 chunks of 16B each.
        // chunk p -> row p>>3, slot p&7; slot holds global chunk (p&7)^(row&7).
        // Each wave writes a 64-chunk run (wave-uniform LDS base + lane*16).
        {
            int r0 = tid >> 3, sl0 = tid & 7;               // chunks 0..511
            int src0 = sl0 ^ (r0 & 7);
            GLL(&SH[(rowBase + r0) * (size_t)DLb + k0 + src0 * 8], Ah + w * 512);
            GLL(&SL[(rowBase + r0) * (size_t)DLb + k0 + src0 * 8], Al + w * 512);
            int c1 = 512 + tid;                             // chunks 512..1023
            int r1 = c1 >> 3, sl1 = c1 & 7;
            int src1 = sl1 ^ (r1 & 7);
            GLL(&SH[(rowBase + r1) * (size_t)DLb + k0 + src1 * 8], Ah + 4096 + w * 512);
            GLL(&SL[(rowBase + r1) * (size_t)DLb + k0 + src1 * 8], Al + 4096 + w * 512);
            if (tid < 128) {                                // chunks 1024..1151
                int c2 = 1024 + tid;
                int r2 = c2 >> 3, sl2 = c2 & 7;
                int src2 = sl2 ^ (r2 & 7);
                GLL(&SH[(rowBase + r2) * (size_t)DLb + k0 + src2 * 8], Ah + 8192 + w * 512);
                GLL(&SL[(rowBase + r2) * (size_t)DLb + k0 + src2 * 8], Al + 8192 + w * 512);
            }
        }
        __syncthreads();
        #pragma unroll
        for (int ks = 0; ks < 2; ks++) {
            short8 bh[3], bl[3];
            #pragma unroll
            for (int g = 0; g < 3; g++) {
                int col = colBase + g * 16 + fr;
                bh[g] = *(const short8*)&WHp[(size_t)col * DLb + k0 + ks * 32 + fq * 8];
                bl[g] = *(const short8*)&WLp[(size_t)col * DLb + k0 + ks * 32 + fq * 8];
            }
            #pragma unroll
            for (int i = 0; i < 9; i++) {
                int row = i * 16 + fr;
                int ra = row * 64 + (((ks * 4 + fq) ^ (row & 7)) << 3);
                short8 ah  = *(const short8*)&Ah[ra];
                short8 al4 = *(const short8*)&Al[ra];
                #pragma unroll
                for (int g = 0; g < 3; g++) {
                    acc[i][g] = __builtin_amdgcn_mfma_f32_16x16x32_bf16(ah,  bh[g], acc[i][g], 0, 0, 0);
                    acc[i][g] = __builtin_amdgcn_mfma_f32_16x16x32_bf16(ah,  bl[g], acc[i][g], 0, 0, 0);
                    acc[i][g] = __builtin_amdgcn_mfma_f32_16x16x32_bf16(al4, bh[g], acc[i][g], 0, 0, 0);
                }
            }
        }
        __syncthreads();
    }

    // phase 1: q (cols 0..127, p>=1 rows) and k (cols 128..255) into LDS, +bias
    #pragma unroll
    for (int g = 0; g < 3; g++) {
        int cg = colBase + g * 16;
        if (cg < 256) {
            float bv = bias[cg + fr];
            #pragma unroll
            for (int i = 0; i < 9; i++) {
                #pragma unroll
                for (int rr = 0; rr < 4; rr++) {
                    int lr = i * 16 + fq * 4 + rr;
                    float v = acc[i][g][rr] + bv;
                    if (cg < 128) {
                        int t = lr / 9, p = lr - t * 9;
                        if (p) qbuf[(t * 8 + p - 1) * 132 + cg + fr] = v;
                    } else {
                        kbuf[lr * 132 + (cg - 128) + fr] = v;
                    }
                }
            }
        }
    }
    __syncthreads();

    // phase 2: attnw for (t, h, ii=1..8) — 512 threads, one each.
    // float4 LDS loads, scalar serial accumulation (d2 ascending) == old order.
    {
        int t = tid >> 5, h = (tid >> 3) & 3, ii = 1 + (tid & 7);
        const float* qrow = &qbuf[(t * 8 + ii - 1) * 132 + h * HDh];
        float4 q4[8];
        #pragma unroll
        for (int q = 0; q < 8; q++) q4[q] = *(const float4*)&qrow[q * 4];
        float sc[NPOS];
        float mx = -1e30f;
        for (int j = 0; j < NPOS; j++) {
            const float* krow = &kbuf[(t * 9 + j) * 132 + h * HDh];
            float s = 0.0f;
            #pragma unroll
            for (int q = 0; q < 8; q++) {
                float4 k4 = *(const float4*)&krow[q * 4];
                s += q4[q].x * k4.x;
                s += q4[q].y * k4.y;
                s += q4[q].z * k4.z;
                s += q4[q].w * k4.w;
            }
            s *= 0.17677669529663687f;
            sc[j] = s;
            mx = fmaxf(mx, s);
        }
        float se = 0.0f;
        for (int j = 0; j < NPOS; j++) { sc[j] = expf(sc[j] - mx); se += sc[j]; }
        float inv = 1.0f / se;
        for (int j = 0; j < NPOS; j++) attnw[((t * 4 + h) * 8 + (ii - 1)) * 9 + j] = sc[j] * inv;
    }
    __syncthreads();

    // phase 3: v (cols 256..383) into LDS (aliases q region), +bias
    #pragma unroll
    for (int g = 0; g < 3; g++) {
        int cg = colBase + g * 16;
        if (cg >= 256) {
            float bv = bias[cg + fr];
            #pragma unroll
            for (int i = 0; i < 9; i++) {
                #pragma unroll
                for (int rr = 0; rr < 4; rr++) {
                    int lr = i * 16 + fq * 4 + rr;
                    vbuf[lr * 132 + (cg - 256) + fr] = acc[i][g][rr] + bv;
                }
            }
        }
    }
    __syncthreads();

    // phase 4: o[t*8+pm1][d] = sum_j attnw * v — thread = (t, dq); each v-row quad
    // read ONCE and reused across the 8 output rows. j ascending, per-component
    // serial per output == old order -> bit-identical.
    {
        int t = tid >> 5, dq = tid & 31;
        int h = dq >> 3;
        const float* awb = &attnw[(t * 4 + h) * 8 * 9];
        float4 s[8];
        #pragma unroll
        for (int p = 0; p < 8; p++) { s[p].x = 0.0f; s[p].y = 0.0f; s[p].z = 0.0f; s[p].w = 0.0f; }
        #pragma unroll
        for (int j = 0; j < NPOS; j++) {
            float4 v4 = *(const float4*)&vbuf[(t * 9 + j) * 132 + dq * 4];
            #pragma unroll
            for (int p = 0; p < 8; p++) {
                float a = awb[p * 9 + j];
                s[p].x += a * v4.x; s[p].y += a * v4.y;
                s[p].z += a * v4.z; s[p].w += a * v4.w;
            }
        }
        float* obase = &og[((size_t)(blockIdx.x * 16 + t) * 8) * DLb + dq * 4];
        #pragma unroll
        for (int p = 0; p < 8; p++)
            *(float4*)&obase[(size_t)p * DLb] = s[p];
    }
}

// ---------------- K4cd: logits = LN(o@aow^T + aob + residual) . u + c0 (fused, no s2/rk) ----------------
__global__ __launch_bounds__(256) void k4cd(const float* __restrict__ A,
                                            const float* __restrict__ W,
                                            const float* __restrict__ bias,
                                            const unsigned short* __restrict__ seqh,
                                            const unsigned short* __restrict__ seql,
                                            const float* __restrict__ nw,
                                            const float* __restrict__ nb,
                                            const float* __restrict__ uv,
                                            const float* __restrict__ c0v,
                                            float* __restrict__ logits)
{
    __shared__ __attribute__((aligned(16))) float As[16][132];
    __shared__ __attribute__((aligned(16))) float Bs[16][132];
    __shared__ float redS[128][17];
    __shared__ float mstat[128][2];
    int tid = threadIdx.x;
    int tx = tid & 15, ty = tid >> 4;
    int row0 = blockIdx.y * 128;
    float acc[8][8] = {};
    for (int k0 = 0; k0 < DLb; k0 += 16) {
        #pragma unroll
        for (int i = 0; i < 2; i++) {
            int L = i * 256 + tid;
            int r = L >> 2, kq = (L & 3) * 4;
            float4 a4 = *(const float4*)&A[(size_t)(row0 + r) * DLb + k0 + kq];
            float4 b4 = *(const float4*)&W[(size_t)r * DLb + k0 + kq];
            As[kq + 0][r] = a4.x; As[kq + 1][r] = a4.y; As[kq + 2][r] = a4.z; As[kq + 3][r] = a4.w;
            Bs[kq + 0][r] = b4.x; Bs[kq + 1][r] = b4.y; Bs[kq + 2][r] = b4.z; Bs[kq + 3][r] = b4.w;
        }
        __syncthreads();
        #pragma unroll
        for (int kk = 0; kk < 16; kk++) {
            float4 a0 = *(const float4*)&As[kk][ty * 4];
            float4 a1 = *(const float4*)&As[kk][64 + ty * 4];
            float4 b0 = *(const float4*)&Bs[kk][tx * 4];
            float4 b1 = *(const float4*)&Bs[kk][64 + tx * 4];
            float ar[8] = {a0.x, a0.y, a0.z, a0.w, a1.x, a1.y, a1.z, a1.w};
            float bc[8] = {b0.x, b0.y, b0.z, b0.w, b1.x, b1.y, b1.z, b1.w};
            #pragma unroll
            for (int i = 0; i < 8; i++)
                #pragma unroll
                for (int j = 0; j < 8; j++)
                    acc[i][j] += ar[i] * bc[j];
        }
        __syncthreads();
    }
    int b = row0 >> 14;
    float4 bb0 = *(const float4*)&bias[tx * 4];
    float4 bb1 = *(const float4*)&bias[64 + tx * 4];
    // bias + residual; row-sum partials for mean
    #pragma unroll
    for (int i = 0; i < 8; i++) {
        int rl = (i < 4) ? (ty * 4 + i) : (64 + ty * 4 + (i - 4));
        int m = row0 + rl;
        size_t roff = (size_t)(m >> 3) * SEQSTR + (size_t)((m & 7) + 1) * DLb;
        float4 r0 = rec4(&seqh[roff + tx * 4], &seql[roff + tx * 4]);
        float4 r1 = rec4(&seqh[roff + 64 + tx * 4], &seql[roff + 64 + tx * 4]);
        acc[i][0] += bb0.x + r0.x; acc[i][1] += bb0.y + r0.y;
        acc[i][2] += bb0.z + r0.z; acc[i][3] += bb0.w + r0.w;
        acc[i][4] += bb1.x + r1.x; acc[i][5] += bb1.y + r1.y;
        acc[i][6] += bb1.z + r1.z; acc[i][7] += bb1.w + r1.w;
        float ps = 0.0f;
        #pragma unroll
        for (int j = 0; j < 8; j++) ps += acc[i][j];
        redS[rl][tx] = ps;
    }
    __syncthreads();
    if (tid < 128) {
        float s = 0.0f;
        #pragma unroll
        for (int t = 0; t < 16; t++) s += redS[tid][t];
        mstat[tid][0] = s * (1.0f / DLb);
    }
    __syncthreads();
    #pragma unroll
    for (int i = 0; i < 8; i++) {
        int rl = (i < 4) ? (ty * 4 + i) : (64 + ty * 4 + (i - 4));
        float m = mstat[rl][0];
        float pv = 0.0f;
        #pragma unroll
        for (int j = 0; j < 8; j++) { float df = acc[i][j] - m; pv += df * df; }
        redS[rl][tx] = pv;
    }
    __syncthreads();
    if (tid < 128) {
        float s = 0.0f;
        #pragma unroll
        for (int t = 0; t < 16; t++) s += redS[tid][t];
        mstat[tid][1] = 1.0f / sqrtf(s * (1.0f / DLb) + 1e-5f);
    }
    __syncthreads();
    const float* u = uv + b * DLb;
    float4 nw0 = *(const float4*)&nw[tx * 4];
    float4 nw1 = *(const float4*)&nw[64 + tx * 4];
    float4 nb0 = *(const float4*)&nb[tx * 4];
    float4 nb1 = *(const float4*)&nb[64 + tx * 4];
    float4 u0 = *(const float4*)&u[tx * 4];
    float4 u1 = *(const float4*)&u[64 + tx * 4];
    #pragma unroll
    for (int i = 0; i < 8; i++) {
        int rl = (i < 4) ? (ty * 4 + i) : (64 + ty * 4 + (i - 4));
        float m = mstat[rl][0], istd = mstat[rl][1];
        float ps;
        ps  = ((acc[i][0] - m) * istd * nw0.x + nb0.x) * u0.x;
        ps += ((acc[i][1] - m) * istd * nw0.y + nb0.y) * u0.y;
        ps += ((acc[i][2] - m) * istd * nw0.z + nb0.z) * u0.z;
        ps += ((acc[i][3] - m) * istd * nw0.w + nb0.w) * u0.w;
        ps += ((acc[i][4] - m) * istd * nw1.x + nb1.x) * u1.x;
        ps += ((acc[i][5] - m) * istd * nw1.y + nb1.y) * u1.y;
        ps += ((acc[i][6] - m) * istd * nw1.z + nb1.z) * u1.z;
        ps += ((acc[i][7] - m) * istd * nw1.w + nb1.w) * u1.w;
        redS[rl][tx] = ps;
    }
    __syncthreads();
    if (tid < 128) {
        float s = 0.0f;
        #pragma unroll
        for (int t = 0; t < 16; t++) s += redS[tid][t];
        logits[row0 + tid] = (s + c0v[b]) * 0.08838834764831845f;   // 1/sqrt(128)
    }
}

// ---------------- K4e6: per-token softmax + top-3 + wsel, fused aux partials ----------------
__global__ __launch_bounds__(256) void k4e6(const float* __restrict__ logits,
                                            float* __restrict__ wsel,
                                            float* __restrict__ part)
{
    int tid = threadIdx.x;
    int n = blockIdx.x * 256 + tid;
    float lg[EE];
    float4 l0 = *(const float4*)&logits[(size_t)n * EE];
    float4 l1 = *(const float4*)&logits[(size_t)n * EE + 4];
    lg[0] = l0.x; lg[1] = l0.y; lg[2] = l0.z; lg[3] = l0.w;
    lg[4] = l1.x; lg[5] = l1.y; lg[6] = l1.z; lg[7] = l1.w;
    float mx = lg[0];
    #pragma unroll
    for (int e = 1; e < EE; e++) mx = fmaxf(mx, lg[e]);
    float pr[EE];
    float se = 0.0f;
    #pragma unroll
    for (int e = 0; e < EE; e++) { pr[e] = expf(lg[e] - mx); se += pr[e]; }
    float inv = 1.0f / se;
    #pragma unroll
    for (int e = 0; e < EE; e++) pr[e] *= inv;
    bool used[EE] = {};
    int sel[KK];
    float sw = 0.0f;
    for (int t = 0; t < KK; t++) {
        int bi = 0; float bv = -1e30f;
        for (int e = 0; e < EE; e++)
            if (!used[e] && pr[e] > bv) { bv = pr[e]; bi = e; }
        used[bi] = true; sel[t] = bi; sw += pr[bi];
    }
    float invsw = 1.0f / sw;
    float w8[EE];
    #pragma unroll
    for (int e = 0; e < EE; e++) w8[e] = 0.0f;
    for (int t = 0; t < KK; t++) w8[sel[t]] = pr[sel[t]] * invsw;
    float4 w0, w1;
    w0.x = w8[0]; w0.y = w8[1]; w0.z = w8[2]; w0.w = w8[3];
    w1.x = w8[4]; w1.y = w8[5]; w1.z = w8[6]; w1.w = w8[7];
    *(float4*)&wsel[(size_t)n * EE] = w0;
    *(float4*)&wsel[(size_t)n * EE + 4] = w1;

    // fused k6a: block reduction of probs and selection counts (same values/order)
    __shared__ float bp[256][EE];
    __shared__ float bc[256][EE];
    #pragma unroll
    for (int e = 0; e < EE; e++) {
        bp[tid][e] = pr[e];
        bc[tid][e] = (w8[e] > 0.0f) ? 1.0f : 0.0f;
    }
    __syncthreads();
    for (int s = 128; s > 0; s >>= 1) {
        if (tid < s) {
            #pragma unroll
            for (int e = 0; e < EE; e++) {
                bp[tid][e] += bp[tid + s][e];
                bc[tid][e] += bc[tid + s][e];
            }
        }
        __syncthreads();
    }
    if (tid < EE) {
        part[blockIdx.x * 16 + tid] = bp[0][tid];
        part[blockIdx.x * 16 + 8 + tid] = bc[0][tid];
    }
}

// ---------------- K5pre: a_bf16[n][k] = wsel[n][k>>7] * gelu(rec(seq) - pe) ----------------
__global__ __launch_bounds__(256) void k5pre(const unsigned short* __restrict__ seqh,
                                             const unsigned short* __restrict__ seql,
                                             const float* __restrict__ pe,
                                             const float* __restrict__ wsel,
                                             unsigned short* __restrict__ abf)
{
    size_t g = ((size_t)blockIdx.x * 256 + threadIdx.x) * 8;
    int n = (int)(g >> 10), k0 = (int)(g & 1023);
    int e = k0 >> 7;
    float w = wsel[(size_t)n * EE + e];
    size_t soff = (size_t)n * SEQSTR + DLb + k0;
    ushort8 hv = *(const ushort8*)&seqh[soff];
    ushort8 lv = *(const ushort8*)&seql[soff];
    float4 p0 = *(const float4*)&pe[k0];
    float4 p1 = *(const float4*)&pe[k0 + 4];
    float pp[8] = {p0.x, p0.y, p0.z, p0.w, p1.x, p1.y, p1.z, p1.w};
    ushort8 o;
    #pragma unroll
    for (int i = 0; i < 8; i++) {
        float v = bf2f(hv[i]) + bf2f(lv[i]) - pp[i];
        o[i] = f2bf(w * gelu_exact(v));
    }
    *(ushort8*)&abf[g] = o;
}

// ---------------- K5t: wupT[m][k] = bf16(wup[k][m]) ----------------
__global__ __launch_bounds__(256) void k5t(const float* __restrict__ wup, unsigned short* __restrict__ wupT) {
    __shared__ float T[64][68];
    int tid = threadIdx.x;
    int k0 = blockIdx.x * 64, m0 = blockIdx.y * 64;
    #pragma unroll
    for (int i = 0; i < 4; i++) {
        int F = i * 256 + tid;
        int r = F >> 4, c4 = (F & 15) * 4;
        *(float4*)&T[r][c4] = *(const float4*)&wup[(size_t)(k0 + r) * DD + m0 + c4];
    }
    __syncthreads();
    #pragma unroll
    for (int i = 0; i < 2; i++) {
        int W = i * 256 + tid;
        int r = W >> 3, c8 = (W & 7) * 8;
        ushort8 o;
        #pragma unroll
        for (int j = 0; j < 8; j++) o[j] = f2bf(T[c8 + j][r]);
        *(ushort8*)&wupT[(size_t)(m0 + r) * DD + k0 + c8] = o;
    }
}

// ---------------- K5: out = a_bf16 @ wupT^T (MFMA, 8-wave, BK=64, swizzled) ----------------
__global__ __launch_bounds__(512, 6) void k5_mfma(const unsigned short* __restrict__ A,
                                                  const unsigned short* __restrict__ B,
                                                  float* __restrict__ C)
{
    __shared__ __attribute__((aligned(16))) unsigned short As[2][128 * 32];
    __shared__ __attribute__((aligned(16))) unsigned short Bs[2][128 * 32];
    int tid = threadIdx.x;
    int lane = tid & 63, wave = tid >> 6;
    int wm = wave & 1, wn = wave >> 1;
    // grid (8,64) = 512 blocks, XCD-chunked swizzle
    int b = blockIdx.y * 8 + blockIdx.x;
    int nbid = (b & 7) * 64 + (b >> 3);
    int row0 = (nbid >> 3) * 128, col0 = (nbid & 7) * 128;
    int fr = lane & 15, fq = lane >> 4;
    f32x4 acc[4][2];
    #pragma unroll
    for (int i = 0; i < 4; i++)
        #pragma unroll
        for (int j = 0; j < 2; j++) acc[i][j] = (f32x4)0.0f;

    for (int k0 = 0; k0 < DD; k0 += 64) {
        stage512(A, row0, DD, k0,      As[0], tid);
        stage512(A, row0, DD, k0 + 32, As[1], tid);
        stage512(B, col0, DD, k0,      Bs[0], tid);
        stage512(B, col0, DD, k0 + 32, Bs[1], tid);
        __syncthreads();
        #pragma unroll
        for (int ks = 0; ks < 2; ks++) {
            short8 af[4], bf[2];
            #pragma unroll
            for (int f = 0; f < 4; f++)
                af[f] = *(const short8*)&As[ks][fragoff(wm * 64 + f * 16 + fr, fq)];
            #pragma unroll
            for (int g = 0; g < 2; g++)
                bf[g] = *(const short8*)&Bs[ks][fragoff(wn * 32 + g * 16 + fr, fq)];
            #pragma unroll
            for (int i = 0; i < 4; i++)
                #pragma unroll
                for (int j = 0; j < 2; j++)
                    acc[i][j] = __builtin_amdgcn_mfma_f32_16x16x32_bf16(af[i], bf[j], acc[i][j], 0, 0, 0);
        }
        __syncthreads();
    }
    #pragma unroll
    for (int i = 0; i < 4; i++) {
        #pragma unroll
        for (int j = 0; j < 2; j++) {
            int gc = col0 + wn * 32 + j * 16 + fr;
            #pragma unroll
            for (int r = 0; r < 4; r++) {
                int gr = row0 + wm * 64 + i * 16 + fq * 4 + r;
                C[(size_t)gr * DD + gc] = acc[i][j][r];
            }
        }
    }
}

// ---------------- K6b: aux loss finalize ----------------
__global__ __launch_bounds__(64) void k6b(const float* __restrict__ part, float* __restrict__ out_aux) {
    int tid = threadIdx.x;
    __shared__ float sums[16];
    if (tid < 16) {
        float s = 0.0f;
        for (int b = 0; b < NN / 256; b++) s += part[b * 16 + tid];
        sums[tid] = s;
    }
    __syncthreads();
    if (tid == 0) {
        float a = 0.0f;
        for (int e = 0; e < EE; e++) a += (sums[e] / NN) * (sums[8 + e] / NN);
        out_aux[0] = EE * a;
    }
}

extern "C" void kernel_launch(void* const* d_in, const int* in_sizes, int n_in,
                              void* d_out, int out_size, void* d_ws, size_t ws_size,
                              hipStream_t stream) {
    const float* x     = (const float*)d_in[0];
    const float* wdown = (const float*)d_in[1];
    const float* pe    = (const float*)d_in[2];
    const float* gpw   = (const float*)d_in[3];
    const float* gpb   = (const float*)d_in[4];
    const float* aiw   = (const float*)d_in[5];
    const float* aib   = (const float*)d_in[6];
    const float* aow   = (const float*)d_in[7];
    const float* aob   = (const float*)d_in[8];
    const float* nw    = (const float*)d_in[9];
    const float* nb    = (const float*)d_in[10];
    const float* rq1w  = (const float*)d_in[11];
    const float* rq1b  = (const float*)d_in[12];
    const float* rqlnw = (const float*)d_in[13];
    const float* rqlnb = (const float*)d_in[14];
    const float* rq2w  = (const float*)d_in[15];
    const float* rq2b  = (const float*)d_in[16];
    const float* rkw   = (const float*)d_in[17];
    const float* rkb   = (const float*)d_in[18];
    const float* wup   = (const float*)d_in[19];

    float* out = (float*)d_out;

    // workspace layout
    unsigned short* seqh = (unsigned short*)d_ws;                    // NN*SEQSTR us
    unsigned short* seql = seqh + (size_t)NN * SEQSTR;               // NN*SEQSTR us
    float* xregion = (float*)(seql + (size_t)NN * SEQSTR);           // NN*DD floats
    unsigned short* xh = (unsigned short*)xregion;                   // NN*DD us
    unsigned short* xl = xh + (size_t)NN * DD;                       // NN*DD us
    float* o = xregion;                                              // alias (xh/xl dead after k3s)
    unsigned short* abf = (unsigned short*)xregion;                  // alias (o dead after k4cd)
    float* region = xregion + (size_t)NN * DD;                       // 8.39M floats
    float* probs  = region + (size_t)65536 * 128;                    // (reserved, unused)
    float* wsel   = probs + (size_t)NN * EE;
    float* logits = wsel + (size_t)NN * EE;
    float* partial= logits + (size_t)NN * EE;
    float* mean_x = partial + (size_t)BB * NCH * DD;
    float* gctx   = mean_x + (size_t)BB * DD;
    float* uv     = gctx + (size_t)BB * DLb;                         // BB*DLb
    float* c0v    = uv + (size_t)BB * DLb;                           // BB
    float* k6part = c0v + 64;                                        // 512 floats
    unsigned short* wupT = (unsigned short*)(k6part + 512);          // 1M us
    unsigned short* wdh  = wupT + (size_t)DD * DD;                   // 1M us
    unsigned short* wdl  = wdh + (size_t)DD * DD;                    // 1M us
    unsigned short* aiwh = wdl + (size_t)DD * DD;                    // 48K us
    unsigned short* aiwl = aiwh + (size_t)384 * DLb;                 // 48K us

    // fused pre-split pass (wdown + aiw in one launch; x split fused into k1a)
    hipLaunchKernelGGL(ksplit2, dim3((DD * DD / 8 + 384 * DLb / 8) / 256), dim3(256), 0, stream,
                       wdown, wdh, wdl, DD * DD / 8, aiw, aiwh, aiwl, 384 * DLb / 8);

    hipLaunchKernelGGL(k1a, dim3(DD / 256, BB, NCH), dim3(256), 0, stream, x, partial, xh, xl);
    hipLaunchKernelGGL(k1b, dim3(DD / 256, BB), dim3(256), 0, stream, partial, mean_x);
    hipLaunchKernelGGL(k2_batch, dim3(BB), dim3(DLb), 0, stream,
                       mean_x, gpw, gpb, rq1w, rq1b, rqlnw, rqlnb, rq2w, rq2b, rkw, rkb,
                       gctx, uv, c0v);
    hipLaunchKernelGGL(k3s, dim3((EE * DLb) / 128, NN / 128), dim3(512), 0, stream,
                       xh, xl, wdh, wdl, pe, gctx, seqh, seql);
    hipLaunchKernelGGL(k4f, dim3(NN / 16), dim3(512), 0, stream,
                       seqh, seql, aiwh, aiwl, aib, o);
    hipLaunchKernelGGL(k4cd, dim3(1, NN * EE / 128), dim3(256), 0, stream,
                       o, aow, aob, seqh, seql, nw, nb, uv, c0v, logits);
    hipLaunchKernelGGL(k4e6, dim3(NN / 256), dim3(256), 0, stream, logits, wsel, k6part);
    hipLaunchKernelGGL(k5t, dim3(DD / 64, DD / 64), dim3(256), 0, stream, wup, wupT);
    hipLaunchKernelGGL(k5pre, dim3(NN * DD / (256 * 8)), dim3(256), 0, stream, seqh, seql, pe, wsel, abf);
    hipLaunchKernelGGL(k5_mfma, dim3(DD / 128, NN / 128), dim3(512), 0, stream, abf, wupT, out);
    hipLaunchKernelGGL(k6b, dim3(1), dim3(64), 0, stream, k6part, out + (size_t)NN * DD);
}

// Round 13
// 337.251 us; speedup vs baseline: 1.0778x; 1.0778x over previous
//
#include <hip/hip_runtime.h>
#include <hip/hip_bf16.h>
#include <math.h>

#define BB 4
#define TT 2048
#define DD 1024
#define DLb 128
#define EE 8
#define HH 4
#define KK 3
#define HDh 32
#define NN (BB*TT)
#define NPOS 9
#define NCH 16
#define CHL (TT/NCH)
#define SEQSTR (NPOS*DLb)   // 1152

typedef __attribute__((ext_vector_type(8))) short short8;
typedef __attribute__((ext_vector_type(4))) float f32x4;
typedef __attribute__((ext_vector_type(8))) unsigned short ushort8;
typedef __attribute__((ext_vector_type(4))) unsigned short ushort4v;

// async global->LDS DMA, 16B per lane; LDS dest = wave-uniform base + lane*16
#define GLL(gptr, lptr) \
    __builtin_amdgcn_global_load_lds((const __attribute__((address_space(1))) unsigned int*)(gptr), \
                                     (__attribute__((address_space(3))) unsigned int*)(lptr), 16, 0, 0)

__device__ __forceinline__ float gelu_exact(float v) {
    return 0.5f * v * (1.0f + erff(v * 0.70710678118654752440f));
}

__device__ __forceinline__ unsigned short f2bf(float x) {
    __hip_bfloat16 h = __float2bfloat16(x);
    return *reinterpret_cast<unsigned short*>(&h);
}

__device__ __forceinline__ float bf2f(unsigned short u) {
    return __uint_as_float(((unsigned int)u) << 16);
}

__device__ __forceinline__ float4 rec4(const unsigned short* h, const unsigned short* l) {
    ushort4v hv = *(const ushort4v*)h;
    ushort4v lv = *(const ushort4v*)l;
    float4 r;
    r.x = bf2f(hv[0]) + bf2f(lv[0]);
    r.y = bf2f(hv[1]) + bf2f(lv[1]);
    r.z = bf2f(hv[2]) + bf2f(lv[2]);
    r.w = bf2f(hv[3]) + bf2f(lv[3]);
    return r;
}

// --- swizzled staging: 512-thread variant. Panel = 128 rows x 32 cols bf16 (8KB).
// LDS stays linear (GLL requirement); the 16B-chunk permutation is applied on the
// GLOBAL source address (chunk slot s of row r holds global chunk s ^ ((r>>1)&3)).
// Readers apply the same XOR (involution) -> bank-conflict-free fragment reads.
__device__ __forceinline__ void stage512(const unsigned short* __restrict__ G,
                                         size_t rowBase, int L, int k0,
                                         unsigned short* lds, int tid)
{
    int r = tid >> 2;                       // 0..127
    int sl = tid & 3;                       // chunk slot in LDS
    int src = sl ^ ((r >> 1) & 3);          // which global chunk lands here
    GLL(&G[(rowBase + r) * (size_t)L + k0 + src * 8], lds + (tid >> 6) * 512);
}

// fragment-read LDS offset (shorts) for row, chunk fq under the stage512 swizzle
__device__ __forceinline__ int fragoff(int row, int fq) {
    return row * 32 + ((fq ^ ((row >> 1) & 3)) << 3);
}

// ---------------- KPREP: fused preprocessing ----------------
// blocks [0,536):   ksplit2 (wdown hi/lo split, then aiw)   [same index mapping]
// blocks [536,792): k1a (x column-mean partials + x hi/lo split)
// blocks [792,1048): k5t (wup transpose -> bf16 wupT)
// All three regions are independent; branch is block-uniform (barriers safe).
__global__ __launch_bounds__(256) void kprep(
    const float* __restrict__ wdown, unsigned short* __restrict__ wdh, unsigned short* __restrict__ wdl,
    const float* __restrict__ aiw, unsigned short* __restrict__ aiwh, unsigned short* __restrict__ aiwl,
    const float* __restrict__ x, float* __restrict__ partial,
    unsigned short* __restrict__ xh, unsigned short* __restrict__ xl,
    const float* __restrict__ wup, unsigned short* __restrict__ wupT)
{
    __shared__ float T[64][68];
    int bidx = blockIdx.x;
    int tid = threadIdx.x;
    if (bidx < 536) {
        const int n8_1 = DD * DD / 8;       // 131072
        const int n8_2 = 384 * DLb / 8;     // 6144
        int i = bidx * 256 + tid;
        const float* src;
        unsigned short* h;
        unsigned short* l;
        int idx;
        if (i < n8_1) { src = wdown; h = wdh; l = wdl; idx = i; }
        else {
            idx = i - n8_1;
            if (idx >= n8_2) return;
            src = aiw; h = aiwh; l = aiwl;
        }
        size_t g = (size_t)idx * 8;
        float4 a = *(const float4*)&src[g];
        float4 b = *(const float4*)&src[g + 4];
        float vv[8] = {a.x, a.y, a.z, a.w, b.x, b.y, b.z, b.w};
        ushort8 ho, lo;
        #pragma unroll
        for (int j = 0; j < 8; j++) {
            unsigned short hh = f2bf(vv[j]);
            float hf = bf2f(hh);
            ho[j] = hh;
            lo[j] = f2bf(vv[j] - hf);
        }
        *(ushort8*)&h[g] = ho;
        *(ushort8*)&l[g] = lo;
    } else if (bidx < 792) {
        int lb = bidx - 536;                // (dblk, b, c) bijection of orig grid (4,4,16)
        int dblk = lb & 3, b = (lb >> 2) & 3, c = lb >> 4;
        int d = dblk * 256 + tid;
        size_t base = ((size_t)b * TT + (size_t)c * CHL) * DD + d;
        float s = 0.0f;
        for (int t = 0; t < CHL; t++) {
            size_t idx = base + (size_t)t * DD;
            float v = x[idx];
            s += v;
            unsigned short h = f2bf(v);
            xh[idx] = h;
            xl[idx] = f2bf(v - bf2f(h));
        }
        partial[(b * NCH + c) * DD + d] = s;
    } else {
        int lb = bidx - 792;                // orig grid (16,16): x=k-tile, y=m-tile
        int k0 = (lb & 15) * 64, m0 = (lb >> 4) * 64;
        #pragma unroll
        for (int i = 0; i < 4; i++) {
            int F = i * 256 + tid;
            int r = F >> 4, c4 = (F & 15) * 4;
            *(float4*)&T[r][c4] = *(const float4*)&wup[(size_t)(k0 + r) * DD + m0 + c4];
        }
        __syncthreads();
        #pragma unroll
        for (int i = 0; i < 2; i++) {
            int W = i * 256 + tid;
            int r = W >> 3, c8 = (W & 7) * 8;
            ushort8 o;
            #pragma unroll
            for (int j = 0; j < 8; j++) o[j] = f2bf(T[c8 + j][r]);
            *(ushort8*)&wupT[(size_t)(m0 + r) * DD + k0 + c8] = o;
        }
    }
}

// ---------------- K2: per-batch mean (fused k1b) + gctx + rq chain + router u-vector ----------------
__global__ __launch_bounds__(128) void k2_batch(
    const float* __restrict__ partial,
    const float* __restrict__ gpw, const float* __restrict__ gpb,
    const float* __restrict__ rq1w, const float* __restrict__ rq1b,
    const float* __restrict__ lnw, const float* __restrict__ lnb,
    const float* __restrict__ rq2w, const float* __restrict__ rq2b,
    const float* __restrict__ rkw, const float* __restrict__ rkb,
    float* __restrict__ gctx, float* __restrict__ uv, float* __restrict__ c0v)
{
    int b = blockIdx.x, d = threadIdx.x;
    __shared__ __attribute__((aligned(16))) float mxs[DD];
    __shared__ __attribute__((aligned(16))) float g[DLb];
    __shared__ __attribute__((aligned(16))) float t1[DLb];
    __shared__ __attribute__((aligned(16))) float act[DLb];
    __shared__ __attribute__((aligned(16))) float rqs[DLb];
    __shared__ float red[2];
    // fused k1b: mean over the 16 chunk-partials (c ascending == old order)
    #pragma unroll
    for (int i = 0; i < 8; i++) {
        int dd = i * 128 + d;
        float s = 0.0f;
        for (int c = 0; c < NCH; c++) s += partial[(b * NCH + c) * DD + dd];
        mxs[dd] = s * (1.0f / TT);
    }
    __syncthreads();
    {
        const float4* wrow = (const float4*)(gpw + (size_t)d * DD);
        const float4* mx4  = (const float4*)mxs;
        float s = gpb[d];
        for (int k = 0; k < DD / 4; k++) {
            float4 w = wrow[k], m = mx4[k];
            s += w.x * m.x + w.y * m.y + w.z * m.z + w.w * m.w;
        }
        g[d] = s;
        gctx[b * DLb + d] = s;
    }
    __syncthreads();
    {
        float s = rq1b[d];
        for (int k = 0; k < DLb; k++) s += g[k] * rq1w[d * DLb + k];
        t1[d] = s;
    }
    __syncthreads();
    if (d == 0) {
        float m = 0.0f;
        for (int i = 0; i < DLb; i++) m += t1[i];
        m *= (1.0f / DLb);
        float v = 0.0f;
        for (int i = 0; i < DLb; i++) { float df = t1[i] - m; v += df * df; }
        v *= (1.0f / DLb);
        red[0] = m; red[1] = 1.0f / sqrtf(v + 1e-5f);
    }
    __syncthreads();
    {
        float xn = (t1[d] - red[0]) * red[1] * lnw[d] + lnb[d];
        act[d] = gelu_exact(xn);
    }
    __syncthreads();
    {
        float s = rq2b[d];
        for (int k = 0; k < DLb; k++) s += act[k] * rq2w[d * DLb + k];
        rqs[d] = s;
    }
    __syncthreads();
    // u[d] = sum_k rq[k] * rkw[k][d]  (rkw row-major [k][d] -> rkw[k*DLb + d])
    {
        float u = 0.0f;
        for (int k = 0; k < DLb; k++) u += rqs[k] * rkw[(size_t)k * DLb + d];
        uv[b * DLb + d] = u;
    }
    if (d == 0) {
        float c0 = 0.0f;
        for (int k = 0; k < DLb; k++) c0 += rqs[k] * rkb[k];
        c0v[b] = c0;
    }
}

// ---------------- K3s: seq[:,1:,:] = x @ w_down^T + pe  (+ pos-0 fill from gctx) ----------------
// 8-wave split-bf16 MFMA, BK=64, XCD-chunked block swizzle.
__global__ __launch_bounds__(512, 4) void k3s(const unsigned short* __restrict__ XH,
                                              const unsigned short* __restrict__ XL,
                                              const unsigned short* __restrict__ WH,
                                              const unsigned short* __restrict__ WL,
                                              const float* __restrict__ pe,
                                              const float* __restrict__ gctx,
                                              unsigned short* __restrict__ seqh,
                                              unsigned short* __restrict__ seql)
{
    __shared__ __attribute__((aligned(16))) unsigned short Ah[2][128 * 32];
    __shared__ __attribute__((aligned(16))) unsigned short Al[2][128 * 32];
    __shared__ __attribute__((aligned(16))) unsigned short Bh[2][128 * 32];
    __shared__ __attribute__((aligned(16))) unsigned short Bl[2][128 * 32];
    int tid = threadIdx.x;
    int lane = tid & 63, wave = tid >> 6;     // 8 waves
    int wm = wave & 1, wn = wave >> 1;        // 2 x 4 wave grid -> 64x32 per wave
    // XCD-chunked bijective swizzle: grid (8,64) = 512 blocks, 512%8==0.
    int b = blockIdx.y * 8 + blockIdx.x;
    int nbid = (b & 7) * 64 + (b >> 3);
    int row0 = (nbid >> 3) * 128, col0 = (nbid & 7) * 128;
    int fr = lane & 15, fq = lane >> 4;
    f32x4 acc[4][2];
    #pragma unroll
    for (int i = 0; i < 4; i++)
        #pragma unroll
        for (int j = 0; j < 2; j++) acc[i][j] = (f32x4)0.0f;

    for (int k0 = 0; k0 < DD; k0 += 64) {
        stage512(XH, row0, DD, k0,      Ah[0], tid);
        stage512(XH, row0, DD, k0 + 32, Ah[1], tid);
        stage512(XL, row0, DD, k0,      Al[0], tid);
        stage512(XL, row0, DD, k0 + 32, Al[1], tid);
        stage512(WH, col0, DD, k0,      Bh[0], tid);
        stage512(WH, col0, DD, k0 + 32, Bh[1], tid);
        stage512(WL, col0, DD, k0,      Bl[0], tid);
        stage512(WL, col0, DD, k0 + 32, Bl[1], tid);
        __syncthreads();
        #pragma unroll
        for (int ks = 0; ks < 2; ks++) {
            short8 ah[4], al4[4], bh[2], bl4[2];
            #pragma unroll
            for (int f = 0; f < 4; f++) {
                int ra = fragoff(wm * 64 + f * 16 + fr, fq);
                ah[f]  = *(const short8*)&Ah[ks][ra];
                al4[f] = *(const short8*)&Al[ks][ra];
            }
            #pragma unroll
            for (int g = 0; g < 2; g++) {
                int rb = fragoff(wn * 32 + g * 16 + fr, fq);
                bh[g]  = *(const short8*)&Bh[ks][rb];
                bl4[g] = *(const short8*)&Bl[ks][rb];
            }
            #pragma unroll
            for (int i = 0; i < 4; i++)
                #pragma unroll
                for (int j = 0; j < 2; j++) {
                    acc[i][j] = __builtin_amdgcn_mfma_f32_16x16x32_bf16(ah[i],  bh[j],  acc[i][j], 0, 0, 0);
                    acc[i][j] = __builtin_amdgcn_mfma_f32_16x16x32_bf16(ah[i],  bl4[j], acc[i][j], 0, 0, 0);
                    acc[i][j] = __builtin_amdgcn_mfma_f32_16x16x32_bf16(al4[i], bh[j],  acc[i][j], 0, 0, 0);
                }
        }
        __syncthreads();
    }
    #pragma unroll
    for (int j = 0; j < 2; j++) {
        int gc = col0 + wn * 32 + j * 16 + fr;
        float pv = pe[gc];
        #pragma unroll
        for (int i = 0; i < 4; i++) {
            #pragma unroll
            for (int r = 0; r < 4; r++) {
                int gr = row0 + wm * 64 + i * 16 + fq * 4 + r;
                float v = acc[i][j][r] + pv;
                unsigned short h = f2bf(v);
                size_t idx = (size_t)gr * SEQSTR + DLb + gc;
                seqh[idx] = h;
                seql[idx] = f2bf(v - bf2f(h));
            }
        }
    }
    // pos-0 fill (was k2b): col0==0 blocks write gctx into seq position 0 for
    // their 128 tokens. Disjoint addresses from the epilogue above; same ops.
    if (col0 == 0) {
        #pragma unroll
        for (int it = 0; it < 32; it++) {
            int idx = it * 512 + tid;             // 128 tokens x 128 d
            int n = row0 + (idx >> 7), d = idx & 127;
            float v = gctx[(n >> 11) * DLb + d];
            unsigned short h = f2bf(v);
            seqh[(size_t)n * SEQSTR + d] = h;
            seql[(size_t)n * SEQSTR + d] = f2bf(v - bf2f(h));
        }
    }
}

// ---------------- K4f: fused qkv GEMM + attention (BK=64 GEMM, reuse-mapped PV) ----------------
// Block = 16 tokens = 144 contiguous seq rows. 8 waves, 1x8 layout.
// Phase 4: thread=(token, d-quad), each v-row quad read once and reused across the
// token's 8 output rows. All accumulation orders identical to rounds 5/8/11/12 ->
// o bit-identical.
__global__ __launch_bounds__(512, 2) void k4f(const unsigned short* __restrict__ SH,
                                              const unsigned short* __restrict__ SL,
                                              const unsigned short* __restrict__ WHp,
                                              const unsigned short* __restrict__ WLp,
                                              const float* __restrict__ bias,
                                              float* __restrict__ og)
{
    // LDS: 40512 floats = 162,048 B (<= 163,840)
    //  [0, 16896)        qbuf [128][132]   (alias: Ah/Al BK=64 staging; vbuf phase>=3)
    //  [16896, 35904)    kbuf [144][132]
    //  [35904, 40512)    attnw [16][4][8][9]
    __shared__ __attribute__((aligned(16))) float smemf[40512];
    float* qbuf  = smemf;
    float* kbuf  = smemf + 128 * 132;
    float* attnw = smemf + 128 * 132 + 144 * 132;
    float* vbuf  = smemf;                                   // alias (phase >= 3), [144][132]
    unsigned short* Ah = (unsigned short*)smemf;            // [144*64] shorts (4608 floats)
    unsigned short* Al = (unsigned short*)(smemf + 4608);   // [144*64] shorts

    int tid = threadIdx.x;
    int lane = tid & 63, w = tid >> 6;
    int fr = lane & 15, fq = lane >> 4;
    int colBase = w * 48;
    size_t rowBase = (size_t)blockIdx.x * 144;

    f32x4 acc[9][3];
    #pragma unroll
    for (int i = 0; i < 9; i++)
        #pragma unroll
        for (int g = 0; g < 3; g++) acc[i][g] = (f32x4)0.0f;

    for (int k0 = 0; k0 < DLb; k0 += 64) {
        // stage A: 144 rows x 64 cols (hi/lo) = 1152 chunks of 16B each.
        // chunk p -> row p>>3, slot p&7; slot holds global chunk (p&7)^(row&7).
        {
            int r0 = tid >> 3, sl0 = tid & 7;               // chunks 0..511
            int src0 = sl0 ^ (r0 & 7);
            GLL(&SH[(rowBase + r0) * (size_t)DLb + k0 + src0 * 8], Ah + w * 512);
            GLL(&SL[(rowBase + r0) * (size_t)DLb + k0 + src0 * 8], Al + w * 512);
            int c1 = 512 + tid;                             // chunks 512..1023
            int r1 = c1 >> 3, sl1 = c1 & 7;
            int src1 = sl1 ^ (r1 & 7);
            GLL(&SH[(rowBase + r1) * (size_t)DLb + k0 + src1 * 8], Ah + 4096 + w * 512);
            GLL(&SL[(rowBase + r1) * (size_t)DLb + k0 + src1 * 8], Al + 4096 + w * 512);
            if (tid < 128) {                                // chunks 1024..1151
                int c2 = 1024 + tid;
                int r2 = c2 >> 3, sl2 = c2 & 7;
                int src2 = sl2 ^ (r2 & 7);
                GLL(&SH[(rowBase + r2) * (size_t)DLb + k0 + src2 * 8], Ah + 8192 + w * 512);
                GLL(&SL[(rowBase + r2) * (size_t)DLb + k0 + src2 * 8], Al + 8192 + w * 512);
            }
        }
        __syncthreads();
        #pragma unroll
        for (int ks = 0; ks < 2; ks++) {
            short8 bh[3], bl[3];
            #pragma unroll
            for (int g = 0; g < 3; g++) {
                int col = colBase + g * 16 + fr;
                bh[g] = *(const short8*)&WHp[(size_t)col * DLb + k0 + ks * 32 + fq * 8];
                bl[g] = *(const short8*)&WLp[(size_t)col * DLb + k0 + ks * 32 + fq * 8];
            }
            #pragma unroll
            for (int i = 0; i < 9; i++) {
                int row = i * 16 + fr;
                int ra = row * 64 + (((ks * 4 + fq) ^ (row & 7)) << 3);
                short8 ah  = *(const short8*)&Ah[ra];
                short8 al4 = *(const short8*)&Al[ra];
                #pragma unroll
                for (int g = 0; g < 3; g++) {
                    acc[i][g] = __builtin_amdgcn_mfma_f32_16x16x32_bf16(ah,  bh[g], acc[i][g], 0, 0, 0);
                    acc[i][g] = __builtin_amdgcn_mfma_f32_16x16x32_bf16(ah,  bl[g], acc[i][g], 0, 0, 0);
                    acc[i][g] = __builtin_amdgcn_mfma_f32_16x16x32_bf16(al4, bh[g], acc[i][g], 0, 0, 0);
                }
            }
        }
        __syncthreads();
    }

    // phase 1: q (cols 0..127, p>=1 rows) and k (cols 128..255) into LDS, +bias
    #pragma unroll
    for (int g = 0; g < 3; g++) {
        int cg = colBase + g * 16;
        if (cg < 256) {
            float bv = bias[cg + fr];
            #pragma unroll
            for (int i = 0; i < 9; i++) {
                #pragma unroll
                for (int rr = 0; rr < 4; rr++) {
                    int lr = i * 16 + fq * 4 + rr;
                    float v = acc[i][g][rr] + bv;
                    if (cg < 128) {
                        int t = lr / 9, p = lr - t * 9;
                        if (p) qbuf[(t * 8 + p - 1) * 132 + cg + fr] = v;
                    } else {
                        kbuf[lr * 132 + (cg - 128) + fr] = v;
                    }
                }
            }
        }
    }
    __syncthreads();

    // phase 2: attnw for (t, h, ii=1..8) — 512 threads, one each.
    // float4 LDS loads, scalar serial accumulation (d2 ascending) == old order.
    {
        int t = tid >> 5, h = (tid >> 3) & 3, ii = 1 + (tid & 7);
        const float* qrow = &qbuf[(t * 8 + ii - 1) * 132 + h * HDh];
        float4 q4[8];
        #pragma unroll
        for (int q = 0; q < 8; q++) q4[q] = *(const float4*)&qrow[q * 4];
        float sc[NPOS];
        float mx = -1e30f;
        for (int j = 0; j < NPOS; j++) {
            const float* krow = &kbuf[(t * 9 + j) * 132 + h * HDh];
            float s = 0.0f;
            #pragma unroll
            for (int q = 0; q < 8; q++) {
                float4 k4 = *(const float4*)&krow[q * 4];
                s += q4[q].x * k4.x;
                s += q4[q].y * k4.y;
                s += q4[q].z * k4.z;
                s += q4[q].w * k4.w;
            }
            s *= 0.17677669529663687f;
            sc[j] = s;
            mx = fmaxf(mx, s);
        }
        float se = 0.0f;
        for (int j = 0; j < NPOS; j++) { sc[j] = expf(sc[j] - mx); se += sc[j]; }
        float inv = 1.0f / se;
        for (int j = 0; j < NPOS; j++) attnw[((t * 4 + h) * 8 + (ii - 1)) * 9 + j] = sc[j] * inv;
    }
    __syncthreads();

    // phase 3: v (cols 256..383) into LDS (aliases q region), +bias
    #pragma unroll
    for (int g = 0; g < 3; g++) {
        int cg = colBase + g * 16;
        if (cg >= 256) {
            float bv = bias[cg + fr];
            #pragma unroll
            for (int i = 0; i < 9; i++) {
                #pragma unroll
                for (int rr = 0; rr < 4; rr++) {
                    int lr = i * 16 + fq * 4 + rr;
                    vbuf[lr * 132 + (cg - 256) + fr] = acc[i][g][rr] + bv;
                }
            }
        }
    }
    __syncthreads();

    // phase 4: o[t*8+pm1][d] = sum_j attnw * v — thread = (t, dq); each v-row quad
    // read ONCE and reused across the 8 output rows. j ascending, per-component
    // serial per output == old order -> bit-identical.
    {
        int t = tid >> 5, dq = tid & 31;
        int h = dq >> 3;
        const float* awb = &attnw[(t * 4 + h) * 8 * 9];
        float4 s[8];
        #pragma unroll
        for (int p = 0; p < 8; p++) { s[p].x = 0.0f; s[p].y = 0.0f; s[p].z = 0.0f; s[p].w = 0.0f; }
        #pragma unroll
        for (int j = 0; j < NPOS; j++) {
            float4 v4 = *(const float4*)&vbuf[(t * 9 + j) * 132 + dq * 4];
            #pragma unroll
            for (int p = 0; p < 8; p++) {
                float a = awb[p * 9 + j];
                s[p].x += a * v4.x; s[p].y += a * v4.y;
                s[p].z += a * v4.z; s[p].w += a * v4.w;
            }
        }
        float* obase = &og[((size_t)(blockIdx.x * 16 + t) * 8) * DLb + dq * 4];
        #pragma unroll
        for (int p = 0; p < 8; p++)
            *(float4*)&obase[(size_t)p * DLb] = s[p];
    }
}

// ---------------- K4cd: logits = LN(o@aow^T + aob + residual) . u + c0 (fused, no s2/rk) ----------------
__global__ __launch_bounds__(256) void k4cd(const float* __restrict__ A,
                                            const float* __restrict__ W,
                                            const float* __restrict__ bias,
                                            const unsigned short* __restrict__ seqh,
                                            const unsigned short* __restrict__ seql,
                                            const float* __restrict__ nw,
                                            const float* __restrict__ nb,
                                            const float* __restrict__ uv,
                                            const float* __restrict__ c0v,
                                            float* __restrict__ logits)
{
    __shared__ __attribute__((aligned(16))) float As[16][132];
    __shared__ __attribute__((aligned(16))) float Bs[16][132];
    __shared__ float redS[128][17];
    __shared__ float mstat[128][2];
    int tid = threadIdx.x;
    int tx = tid & 15, ty = tid >> 4;
    int row0 = blockIdx.y * 128;
    float acc[8][8] = {};
    for (int k0 = 0; k0 < DLb; k0 += 16) {
        #pragma unroll
        for (int i = 0; i < 2; i++) {
            int L = i * 256 + tid;
            int r = L >> 2, kq = (L & 3) * 4;
            float4 a4 = *(const float4*)&A[(size_t)(row0 + r) * DLb + k0 + kq];
            float4 b4 = *(const float4*)&W[(size_t)r * DLb + k0 + kq];
            As[kq + 0][r] = a4.x; As[kq + 1][r] = a4.y; As[kq + 2][r] = a4.z; As[kq + 3][r] = a4.w;
            Bs[kq + 0][r] = b4.x; Bs[kq + 1][r] = b4.y; Bs[kq + 2][r] = b4.z; Bs[kq + 3][r] = b4.w;
        }
        __syncthreads();
        #pragma unroll
        for (int kk = 0; kk < 16; kk++) {
            float4 a0 = *(const float4*)&As[kk][ty * 4];
            float4 a1 = *(const float4*)&As[kk][64 + ty * 4];
            float4 b0 = *(const float4*)&Bs[kk][tx * 4];
            float4 b1 = *(const float4*)&Bs[kk][64 + tx * 4];
            float ar[8] = {a0.x, a0.y, a0.z, a0.w, a1.x, a1.y, a1.z, a1.w};
            float bc[8] = {b0.x, b0.y, b0.z, b0.w, b1.x, b1.y, b1.z, b1.w};
            #pragma unroll
            for (int i = 0; i < 8; i++)
                #pragma unroll
                for (int j = 0; j < 8; j++)
                    acc[i][j] += ar[i] * bc[j];
        }
        __syncthreads();
    }
    int b = row0 >> 14;
    float4 bb0 = *(const float4*)&bias[tx * 4];
    float4 bb1 = *(const float4*)&bias[64 + tx * 4];
    // bias + residual; row-sum partials for mean
    #pragma unroll
    for (int i = 0; i < 8; i++) {
        int rl = (i < 4) ? (ty * 4 + i) : (64 + ty * 4 + (i - 4));
        int m = row0 + rl;
        size_t roff = (size_t)(m >> 3) * SEQSTR + (size_t)((m & 7) + 1) * DLb;
        float4 r0 = rec4(&seqh[roff + tx * 4], &seql[roff + tx * 4]);
        float4 r1 = rec4(&seqh[roff + 64 + tx * 4], &seql[roff + 64 + tx * 4]);
        acc[i][0] += bb0.x + r0.x; acc[i][1] += bb0.y + r0.y;
        acc[i][2] += bb0.z + r0.z; acc[i][3] += bb0.w + r0.w;
        acc[i][4] += bb1.x + r1.x; acc[i][5] += bb1.y + r1.y;
        acc[i][6] += bb1.z + r1.z; acc[i][7] += bb1.w + r1.w;
        float ps = 0.0f;
        #pragma unroll
        for (int j = 0; j < 8; j++) ps += acc[i][j];
        redS[rl][tx] = ps;
    }
    __syncthreads();
    if (tid < 128) {
        float s = 0.0f;
        #pragma unroll
        for (int t = 0; t < 16; t++) s += redS[tid][t];
        mstat[tid][0] = s * (1.0f / DLb);
    }
    __syncthreads();
    #pragma unroll
    for (int i = 0; i < 8; i++) {
        int rl = (i < 4) ? (ty * 4 + i) : (64 + ty * 4 + (i - 4));
        float m = mstat[rl][0];
        float pv = 0.0f;
        #pragma unroll
        for (int j = 0; j < 8; j++) { float df = acc[i][j] - m; pv += df * df; }
        redS[rl][tx] = pv;
    }
    __syncthreads();
    if (tid < 128) {
        float s = 0.0f;
        #pragma unroll
        for (int t = 0; t < 16; t++) s += redS[tid][t];
        mstat[tid][1] = 1.0f / sqrtf(s * (1.0f / DLb) + 1e-5f);
    }
    __syncthreads();
    const float* u = uv + b * DLb;
    float4 nw0 = *(const float4*)&nw[tx * 4];
    float4 nw1 = *(const float4*)&nw[64 + tx * 4];
    float4 nb0 = *(const float4*)&nb[tx * 4];
    float4 nb1 = *(const float4*)&nb[64 + tx * 4];
    float4 u0 = *(const float4*)&u[tx * 4];
    float4 u1 = *(const float4*)&u[64 + tx * 4];
    #pragma unroll
    for (int i = 0; i < 8; i++) {
        int rl = (i < 4) ? (ty * 4 + i) : (64 + ty * 4 + (i - 4));
        float m = mstat[rl][0], istd = mstat[rl][1];
        float ps;
        ps  = ((acc[i][0] - m) * istd * nw0.x + nb0.x) * u0.x;
        ps += ((acc[i][1] - m) * istd * nw0.y + nb0.y) * u0.y;
        ps += ((acc[i][2] - m) * istd * nw0.z + nb0.z) * u0.z;
        ps += ((acc[i][3] - m) * istd * nw0.w + nb0.w) * u0.w;
        ps += ((acc[i][4] - m) * istd * nw1.x + nb1.x) * u1.x;
        ps += ((acc[i][5] - m) * istd * nw1.y + nb1.y) * u1.y;
        ps += ((acc[i][6] - m) * istd * nw1.z + nb1.z) * u1.z;
        ps += ((acc[i][7] - m) * istd * nw1.w + nb1.w) * u1.w;
        redS[rl][tx] = ps;
    }
    __syncthreads();
    if (tid < 128) {
        float s = 0.0f;
        #pragma unroll
        for (int t = 0; t < 16; t++) s += redS[tid][t];
        logits[row0 + tid] = (s + c0v[b]) * 0.08838834764831845f;   // 1/sqrt(128)
    }
}

// ---------------- K4e6: per-token softmax + top-3 + wsel, fused aux partials ----------------
__global__ __launch_bounds__(256) void k4e6(const float* __restrict__ logits,
                                            float* __restrict__ wsel,
                                            float* __restrict__ part)
{
    int tid = threadIdx.x;
    int n = blockIdx.x * 256 + tid;
    float lg[EE];
    float4 l0 = *(const float4*)&logits[(size_t)n * EE];
    float4 l1 = *(const float4*)&logits[(size_t)n * EE + 4];
    lg[0] = l0.x; lg[1] = l0.y; lg[2] = l0.z; lg[3] = l0.w;
    lg[4] = l1.x; lg[5] = l1.y; lg[6] = l1.z; lg[7] = l1.w;
    float mx = lg[0];
    #pragma unroll
    for (int e = 1; e < EE; e++) mx = fmaxf(mx, lg[e]);
    float pr[EE];
    float se = 0.0f;
    #pragma unroll
    for (int e = 0; e < EE; e++) { pr[e] = expf(lg[e] - mx); se += pr[e]; }
    float inv = 1.0f / se;
    #pragma unroll
    for (int e = 0; e < EE; e++) pr[e] *= inv;
    bool used[EE] = {};
    int sel[KK];
    float sw = 0.0f;
    for (int t = 0; t < KK; t++) {
        int bi = 0; float bv = -1e30f;
        for (int e = 0; e < EE; e++)
            if (!used[e] && pr[e] > bv) { bv = pr[e]; bi = e; }
        used[bi] = true; sel[t] = bi; sw += pr[bi];
    }
    float invsw = 1.0f / sw;
    float w8[EE];
    #pragma unroll
    for (int e = 0; e < EE; e++) w8[e] = 0.0f;
    for (int t = 0; t < KK; t++) w8[sel[t]] = pr[sel[t]] * invsw;
    float4 w0, w1;
    w0.x = w8[0]; w0.y = w8[1]; w0.z = w8[2]; w0.w = w8[3];
    w1.x = w8[4]; w1.y = w8[5]; w1.z = w8[6]; w1.w = w8[7];
    *(float4*)&wsel[(size_t)n * EE] = w0;
    *(float4*)&wsel[(size_t)n * EE + 4] = w1;

    // fused k6a: block reduction of probs and selection counts (same values/order)
    __shared__ float bp[256][EE];
    __shared__ float bc[256][EE];
    #pragma unroll
    for (int e = 0; e < EE; e++) {
        bp[tid][e] = pr[e];
        bc[tid][e] = (w8[e] > 0.0f) ? 1.0f : 0.0f;
    }
    __syncthreads();
    for (int s = 128; s > 0; s >>= 1) {
        if (tid < s) {
            #pragma unroll
            for (int e = 0; e < EE; e++) {
                bp[tid][e] += bp[tid + s][e];
                bc[tid][e] += bc[tid + s][e];
            }
        }
        __syncthreads();
    }
    if (tid < EE) {
        part[blockIdx.x * 16 + tid] = bp[0][tid];
        part[blockIdx.x * 16 + 8 + tid] = bc[0][tid];
    }
}

// ---------------- K5pre: a_bf16[n][k] = wsel[n][k>>7] * gelu(rec(seq) - pe) ----------------
__global__ __launch_bounds__(256) void k5pre(const unsigned short* __restrict__ seqh,
                                             const unsigned short* __restrict__ seql,
                                             const float* __restrict__ pe,
                                             const float* __restrict__ wsel,
                                             unsigned short* __restrict__ abf)
{
    size_t g = ((size_t)blockIdx.x * 256 + threadIdx.x) * 8;
    int n = (int)(g >> 10), k0 = (int)(g & 1023);
    int e = k0 >> 7;
    float w = wsel[(size_t)n * EE + e];
    size_t soff = (size_t)n * SEQSTR + DLb + k0;
    ushort8 hv = *(const ushort8*)&seqh[soff];
    ushort8 lv = *(const ushort8*)&seql[soff];
    float4 p0 = *(const float4*)&pe[k0];
    float4 p1 = *(const float4*)&pe[k0 + 4];
    float pp[8] = {p0.x, p0.y, p0.z, p0.w, p1.x, p1.y, p1.z, p1.w};
    ushort8 o;
    #pragma unroll
    for (int i = 0; i < 8; i++) {
        float v = bf2f(hv[i]) + bf2f(lv[i]) - pp[i];
        o[i] = f2bf(w * gelu_exact(v));
    }
    *(ushort8*)&abf[g] = o;
}

// ---------------- K5: out = a_bf16 @ wupT^T (MFMA, 8-wave, BK=64, swizzled) + fused k6b ----------------
__global__ __launch_bounds__(512, 6) void k5_mfma(const unsigned short* __restrict__ A,
                                                  const unsigned short* __restrict__ B,
                                                  float* __restrict__ C,
                                                  const float* __restrict__ part,
                                                  float* __restrict__ out_aux)
{
    __shared__ __attribute__((aligned(16))) unsigned short As[2][128 * 32];
    __shared__ __attribute__((aligned(16))) unsigned short Bs[2][128 * 32];
    int tid = threadIdx.x;
    int lane = tid & 63, wave = tid >> 6;
    int wm = wave & 1, wn = wave >> 1;
    // fused k6b: block (0,0) wave 0 computes aux loss (part is complete pre-launch).
    // Same sums (lanes<16, b ascending) and e-ascending combine as the old k6b.
    if (blockIdx.x == 0 && blockIdx.y == 0 && wave == 0) {
        float s = 0.0f;
        if (lane < 16) {
            for (int bb = 0; bb < NN / 256; bb++) s += part[bb * 16 + lane];
        }
        float a = 0.0f;
        #pragma unroll
        for (int e = 0; e < EE; e++) {
            float pe_ = __shfl(s, e, 64);
            float ce_ = __shfl(s, 8 + e, 64);
            a += (pe_ / NN) * (ce_ / NN);
        }
        if (lane == 0) out_aux[0] = EE * a;
    }
    // grid (8,64) = 512 blocks, XCD-chunked swizzle
    int b = blockIdx.y * 8 + blockIdx.x;
    int nbid = (b & 7) * 64 + (b >> 3);
    int row0 = (nbid >> 3) * 128, col0 = (nbid & 7) * 128;
    int fr = lane & 15, fq = lane >> 4;
    f32x4 acc[4][2];
    #pragma unroll
    for (int i = 0; i < 4; i++)
        #pragma unroll
        for (int j = 0; j < 2; j++) acc[i][j] = (f32x4)0.0f;

    for (int k0 = 0; k0 < DD; k0 += 64) {
        stage512(A, row0, DD, k0,      As[0], tid);
        stage512(A, row0, DD, k0 + 32, As[1], tid);
        stage512(B, col0, DD, k0,      Bs[0], tid);
        stage512(B, col0, DD, k0 + 32, Bs[1], tid);
        __syncthreads();
        #pragma unroll
        for (int ks = 0; ks < 2; ks++) {
            short8 af[4], bf[2];
            #pragma unroll
            for (int f = 0; f < 4; f++)
                af[f] = *(const short8*)&As[ks][fragoff(wm * 64 + f * 16 + fr, fq)];
            #pragma unroll
            for (int g = 0; g < 2; g++)
                bf[g] = *(const short8*)&Bs[ks][fragoff(wn * 32 + g * 16 + fr, fq)];
            #pragma unroll
            for (int i = 0; i < 4; i++)
                #pragma unroll
                for (int j = 0; j < 2; j++)
                    acc[i][j] = __builtin_amdgcn_mfma_f32_16x16x32_bf16(af[i], bf[j], acc[i][j], 0, 0, 0);
        }
        __syncthreads();
    }
    #pragma unroll
    for (int i = 0; i < 4; i++) {
        #pragma unroll
        for (int j = 0; j < 2; j++) {
            int gc = col0 + wn * 32 + j * 16 + fr;
            #pragma unroll
            for (int r = 0; r < 4; r++) {
                int gr = row0 + wm * 64 + i * 16 + fq * 4 + r;
                C[(size_t)gr * DD + gc] = acc[i][j][r];
            }
        }
    }
}

extern "C" void kernel_launch(void* const* d_in, const int* in_sizes, int n_in,
                              void* d_out, int out_size, void* d_ws, size_t ws_size,
                              hipStream_t stream) {
    const float* x     = (const float*)d_in[0];
    const float* wdown = (const float*)d_in[1];
    const float* pe    = (const float*)d_in[2];
    const float* gpw   = (const float*)d_in[3];
    const float* gpb   = (const float*)d_in[4];
    const float* aiw   = (const float*)d_in[5];
    const float* aib   = (const float*)d_in[6];
    const float* aow   = (const float*)d_in[7];
    const float* aob   = (const float*)d_in[8];
    const float* nw    = (const float*)d_in[9];
    const float* nb    = (const float*)d_in[10];
    const float* rq1w  = (const float*)d_in[11];
    const float* rq1b  = (const float*)d_in[12];
    const float* rqlnw = (const float*)d_in[13];
    const float* rqlnb = (const float*)d_in[14];
    const float* rq2w  = (const float*)d_in[15];
    const float* rq2b  = (const float*)d_in[16];
    const float* rkw   = (const float*)d_in[17];
    const float* rkb   = (const float*)d_in[18];
    const float* wup   = (const float*)d_in[19];

    float* out = (float*)d_out;

    // workspace layout
    unsigned short* seqh = (unsigned short*)d_ws;                    // NN*SEQSTR us
    unsigned short* seql = seqh + (size_t)NN * SEQSTR;               // NN*SEQSTR us
    float* xregion = (float*)(seql + (size_t)NN * SEQSTR);           // NN*DD floats
    unsigned short* xh = (unsigned short*)xregion;                   // NN*DD us
    unsigned short* xl = xh + (size_t)NN * DD;                       // NN*DD us
    float* o = xregion;                                              // alias (xh/xl dead after k3s)
    unsigned short* abf = (unsigned short*)xregion;                  // alias (o dead after k4cd)
    float* region = xregion + (size_t)NN * DD;                       // 8.39M floats
    float* probs  = region + (size_t)65536 * 128;                    // (reserved, unused)
    float* wsel   = probs + (size_t)NN * EE;
    float* logits = wsel + (size_t)NN * EE;
    float* partial= logits + (size_t)NN * EE;
    float* mean_x = partial + (size_t)BB * NCH * DD;                 // (reserved, unused)
    float* gctx   = mean_x + (size_t)BB * DD;
    float* uv     = gctx + (size_t)BB * DLb;                         // BB*DLb
    float* c0v    = uv + (size_t)BB * DLb;                           // BB
    float* k6part = c0v + 64;                                        // 512 floats
    unsigned short* wupT = (unsigned short*)(k6part + 512);          // 1M us
    unsigned short* wdh  = wupT + (size_t)DD * DD;                   // 1M us
    unsigned short* wdl  = wdh + (size_t)DD * DD;                    // 1M us
    unsigned short* aiwh = wdl + (size_t)DD * DD;                    // 48K us
    unsigned short* aiwl = aiwh + (size_t)384 * DLb;                 // 48K us

    // fused preprocessing: wdown/aiw splits + x mean/split + wup transpose
    hipLaunchKernelGGL(kprep, dim3(1048), dim3(256), 0, stream,
                       wdown, wdh, wdl, aiw, aiwh, aiwl, x, partial, xh, xl, wup, wupT);
    hipLaunchKernelGGL(k2_batch, dim3(BB), dim3(DLb), 0, stream,
                       partial, gpw, gpb, rq1w, rq1b, rqlnw, rqlnb, rq2w, rq2b, rkw, rkb,
                       gctx, uv, c0v);
    hipLaunchKernelGGL(k3s, dim3((EE * DLb) / 128, NN / 128), dim3(512), 0, stream,
                       xh, xl, wdh, wdl, pe, gctx, seqh, seql);
    hipLaunchKernelGGL(k4f, dim3(NN / 16), dim3(512), 0, stream,
                       seqh, seql, aiwh, aiwl, aib, o);
    hipLaunchKernelGGL(k4cd, dim3(1, NN * EE / 128), dim3(256), 0, stream,
                       o, aow, aob, seqh, seql, nw, nb, uv, c0v, logits);
    hipLaunchKernelGGL(k4e6, dim3(NN / 256), dim3(256), 0, stream, logits, wsel, k6part);
    hipLaunchKernelGGL(k5pre, dim3(NN * DD / (256 * 8)), dim3(256), 0, stream, seqh, seql, pe, wsel, abf);
    hipLaunchKernelGGL(k5_mfma, dim3(DD / 128, NN / 128), dim3(512), 0, stream,
                       abf, wupT, out, k6part, out + (size_t)NN * DD);
}